// Round 1
// baseline (323.158 us; speedup 1.0000x reference)
//
#include <hip/hip_runtime.h>

typedef __bf16 bf16x8 __attribute__((ext_vector_type(8)));
typedef float f32x4 __attribute__((ext_vector_type(4)));

#define S_LEN 2048
#define DH    64
#define QB    64
#define KB    64
#define LSTR  72   // LDS row stride in bf16 elems (144 B: 16B-aligned, breaks bank stride)

static __device__ __forceinline__ unsigned short f2bf(float f) {
  union { float f; unsigned int u; } x; x.f = f;
  unsigned int r = x.u + 0x7FFFu + ((x.u >> 16) & 1u);  // RNE
  return (unsigned short)(r >> 16);
}

__global__ __launch_bounds__(256) void sdpa_fwd(
    const float* __restrict__ Qg, const float* __restrict__ Kg,
    const float* __restrict__ Vg, float* __restrict__ Og) {
  __shared__ __align__(16) unsigned short Kl[KB * LSTR];       // K tile, row-major [kv][c]
  __shared__ __align__(16) unsigned short Vt[DH * LSTR];       // V tile, transposed [c][kv]
  __shared__ __align__(16) unsigned short Pl[4 * 16 * LSTR];   // P tiles, per-wave [q][kv]

  const int tid  = threadIdx.x;
  const int w    = tid >> 6;    // wave 0..3
  const int lane = tid & 63;
  const int lg   = lane >> 4;   // lane group 0..3
  const int li   = lane & 15;
  const int bh   = blockIdx.y;
  const int q0   = blockIdx.x * QB;
  const size_t base = (size_t)bh * S_LEN * DH;

  // ---- Q fragments, pre-scaled by 1/8 (A-layout: row=li, k=lg*8+j, two K-steps) ----
  bf16x8 aq[2];
  {
    const float* qrow = Qg + base + (size_t)(q0 + w * 16 + li) * DH;
    for (int s = 0; s < 2; ++s) {
      union { unsigned short u[8]; bf16x8 v; } t;
      const float* p = qrow + s * 32 + lg * 8;
      float4 f0 = *(const float4*)(p);
      float4 f1 = *(const float4*)(p + 4);
      t.u[0] = f2bf(f0.x * 0.125f); t.u[1] = f2bf(f0.y * 0.125f);
      t.u[2] = f2bf(f0.z * 0.125f); t.u[3] = f2bf(f0.w * 0.125f);
      t.u[4] = f2bf(f1.x * 0.125f); t.u[5] = f2bf(f1.y * 0.125f);
      t.u[6] = f2bf(f1.z * 0.125f); t.u[7] = f2bf(f1.w * 0.125f);
      aq[s] = t.v;
    }
  }

  f32x4 oacc[4];
  float mrow[4], lrow[4];
  for (int n = 0; n < 4; ++n) oacc[n] = (f32x4){0.f, 0.f, 0.f, 0.f};
  for (int r = 0; r < 4; ++r) { mrow[r] = -1e30f; lrow[r] = 0.f; }

  unsigned short* Pw = &Pl[w * 16 * LSTR];

  for (int kv0 = 0; kv0 < S_LEN; kv0 += KB) {
    __syncthreads();  // previous iteration's LDS reads complete before restage
    // ---- stage K (row-major bf16) and V (transposed bf16), fp32->bf16 on the fly ----
    for (int i = 0; i < 4; ++i) {
      int f4  = tid + i * 256;        // float4 index within 64x64 tile
      int row = f4 >> 4;              // 16 float4 per row
      int c0  = (f4 & 15) * 4;
      size_t goff = base + (size_t)(kv0 + row) * DH + c0;
      float4 kd = *(const float4*)(Kg + goff);
      float4 vd = *(const float4*)(Vg + goff);
      unsigned short* kp = &Kl[row * LSTR + c0];
      kp[0] = f2bf(kd.x); kp[1] = f2bf(kd.y);
      kp[2] = f2bf(kd.z); kp[3] = f2bf(kd.w);
      Vt[(c0 + 0) * LSTR + row] = f2bf(vd.x);
      Vt[(c0 + 1) * LSTR + row] = f2bf(vd.y);
      Vt[(c0 + 2) * LSTR + row] = f2bf(vd.z);
      Vt[(c0 + 3) * LSTR + row] = f2bf(vd.w);
    }
    __syncthreads();

    // ---- S = Q K^T : per-wave 16x64 tile ----
    f32x4 sa[4];
    for (int n = 0; n < 4; ++n) sa[n] = (f32x4){0.f, 0.f, 0.f, 0.f};
    for (int n = 0; n < 4; ++n) {
      for (int s = 0; s < 2; ++s) {
        bf16x8 bk = *(const bf16x8*)&Kl[(n * 16 + li) * LSTR + s * 32 + lg * 8];
        sa[n] = __builtin_amdgcn_mfma_f32_16x16x32_bf16(aq[s], bk, sa[n], 0, 0, 0);
      }
    }

    // ---- online softmax (rows = lg*4+r, cols spread over n and li) ----
    float mt[4];
    for (int r = 0; r < 4; ++r)
      mt[r] = fmaxf(fmaxf(sa[0][r], sa[1][r]), fmaxf(sa[2][r], sa[3][r]));
    for (int mask = 1; mask < 16; mask <<= 1)
      for (int r = 0; r < 4; ++r)
        mt[r] = fmaxf(mt[r], __shfl_xor(mt[r], mask));

    float alpha[4];
    for (int r = 0; r < 4; ++r) {
      float mn = fmaxf(mrow[r], mt[r]);
      alpha[r] = __expf(mrow[r] - mn);
      mrow[r] = mn;
    }
    float p[4][4], ps[4];
    for (int n = 0; n < 4; ++n)
      for (int r = 0; r < 4; ++r)
        p[n][r] = __expf(sa[n][r] - mrow[r]);
    for (int r = 0; r < 4; ++r)
      ps[r] = (p[0][r] + p[1][r]) + (p[2][r] + p[3][r]);
    for (int mask = 1; mask < 16; mask <<= 1)
      for (int r = 0; r < 4; ++r)
        ps[r] += __shfl_xor(ps[r], mask);
    for (int r = 0; r < 4; ++r)
      lrow[r] = lrow[r] * alpha[r] + ps[r];
    for (int n = 0; n < 4; ++n)
      for (int r = 0; r < 4; ++r)
        oacc[n][r] *= alpha[r];

    // ---- P -> per-wave LDS (D-layout scatter), reload in A-layout ----
    for (int n = 0; n < 4; ++n)
      for (int r = 0; r < 4; ++r)
        Pw[(lg * 4 + r) * LSTR + n * 16 + li] = f2bf(p[n][r]);

    bf16x8 ap[2];
    for (int s = 0; s < 2; ++s)
      ap[s] = *(const bf16x8*)&Pw[li * LSTR + s * 32 + lg * 8];

    // ---- O += P V ----
    for (int n = 0; n < 4; ++n) {
      for (int s = 0; s < 2; ++s) {
        bf16x8 bv = *(const bf16x8*)&Vt[(n * 16 + li) * LSTR + s * 32 + lg * 8];
        oacc[n] = __builtin_amdgcn_mfma_f32_16x16x32_bf16(ap[s], bv, oacc[n], 0, 0, 0);
      }
    }
  }

  // ---- epilogue: O / l ----
  for (int r = 0; r < 4; ++r) {
    float inv = 1.0f / lrow[r];
    size_t rowoff = base + (size_t)(q0 + w * 16 + lg * 4 + r) * DH;
    for (int n = 0; n < 4; ++n)
      Og[rowoff + n * 16 + li] = oacc[n][r] * inv;
  }
}

extern "C" void kernel_launch(void* const* d_in, const int* in_sizes, int n_in,
                              void* d_out, int out_size, void* d_ws, size_t ws_size,
                              hipStream_t stream) {
  const float* Qg = (const float*)d_in[0];
  const float* Kg = (const float*)d_in[1];
  const float* Vg = (const float*)d_in[2];
  float* Og = (float*)d_out;
  dim3 grid(S_LEN / QB, 64);  // 32 q-tiles x (N*H)=64
  dim3 block(256);
  sdpa_fwd<<<grid, block, 0, stream>>>(Qg, Kg, Vg, Og);
}

// Round 2
// 122.563 us; speedup vs baseline: 2.6367x; 2.6367x over previous
//
#include <hip/hip_runtime.h>

typedef __bf16 bf16x8 __attribute__((ext_vector_type(8)));
typedef float f32x4 __attribute__((ext_vector_type(4)));
typedef unsigned short ushort_t;

#define S_LEN 2048
#define DH    64
#define NH    64                      // N*H = 8*8 heads
#define KB    64
#define NT    (S_LEN / KB)            // 32 kv tiles
#define QB    128
#define TILE_ELEMS (KB * DH)          // 4096 bf16 per packed tile (8 KB)
#define HEAD_WS    (NT * TILE_ELEMS)  // elems per head per tensor
#define WS_NEEDED  (2ull * NH * HEAD_WS * 2ull)  // bytes

#define QSCALE 0.18033688011112043f   // (1/8) * log2(e)

#if __has_builtin(__builtin_amdgcn_exp2f)
#define EXP2(x) __builtin_amdgcn_exp2f(x)
#else
#define EXP2(x) __expf((x) * 0.6931471805599453f)
#endif

static __device__ __forceinline__ unsigned int f32u(float f) {
  union { float f; unsigned int u; } x; x.f = f; return x.u;
}
// bf16 round-half-up (1 VALU + trunc-store folds to d16_hi)
static __device__ __forceinline__ ushort_t bf_hu(float f) {
  return (ushort_t)((f32u(f) + 0x8000u) >> 16);
}
// bf16 RNE (for round-1 fallback kernel)
static __device__ __forceinline__ ushort_t f2bf(float f) {
  unsigned int u = f32u(f);
  return (ushort_t)((u + 0x7FFFu + ((u >> 16) & 1u)) >> 16);
}

static __device__ __forceinline__ void gl_lds16(const ushort_t* g, ushort_t* l) {
  auto gp = reinterpret_cast<const __attribute__((address_space(1))) char*>(
      reinterpret_cast<uintptr_t>(g));
  auto lp = reinterpret_cast<__attribute__((address_space(3))) char*>(
      (unsigned int)reinterpret_cast<uintptr_t>(l));
  __builtin_amdgcn_global_load_lds(gp, lp, 16, 0, 0);  // dst = lp + lane*16
}

// ---------------- prep: K -> bf16 packed+swizzled, V -> bf16 transposed packed+swizzled ----
// packed tile layout: elem (row, col) at byte  row*128 + (((col>>3) ^ (row&7))<<4) + (col&7)*2
__global__ __launch_bounds__(256) void prep_kv(
    const float* __restrict__ Kg, const float* __restrict__ Vg,
    ushort_t* __restrict__ Kws, ushort_t* __restrict__ Vws) {
  __shared__ float Vl[DH * 65];
  const int tid = threadIdx.x;
  const int tile = blockIdx.x, head = blockIdx.y;
  const size_t gbase = ((size_t)head * S_LEN + (size_t)tile * KB) * DH;
  ushort_t* kdst = Kws + ((size_t)head * NT + tile) * TILE_ELEMS;
  ushort_t* vdst = Vws + ((size_t)head * NT + tile) * TILE_ELEMS;

#pragma unroll
  for (int i = 0; i < 4; ++i) {
    int idx = tid + i * 256;
    int row = idx >> 4;            // kv row
    int c0  = (idx & 15) * 4;      // channel start
    float4 kd = *(const float4*)(Kg + gbase + row * DH + c0);
    float4 vd = *(const float4*)(Vg + gbase + row * DH + c0);
    int chunk = (c0 >> 3) ^ (row & 7);
    ushort4 ko;
    ko.x = f2bf(kd.x); ko.y = f2bf(kd.y); ko.z = f2bf(kd.z); ko.w = f2bf(kd.w);
    *(ushort4*)(kdst + row * 64 + chunk * 8 + (c0 & 7)) = ko;
    Vl[(c0 + 0) * 65 + row] = vd.x;
    Vl[(c0 + 1) * 65 + row] = vd.y;
    Vl[(c0 + 2) * 65 + row] = vd.z;
    Vl[(c0 + 3) * 65 + row] = vd.w;
  }
  __syncthreads();
#pragma unroll
  for (int i = 0; i < 4; ++i) {
    int idx = tid + i * 256;
    int c  = idx >> 4;             // channel row of V^T
    int k0 = (idx & 15) * 4;       // kv start
    int chunk = (k0 >> 3) ^ (c & 7);
    ushort4 vo;
    vo.x = f2bf(Vl[c * 65 + k0 + 0]);
    vo.y = f2bf(Vl[c * 65 + k0 + 1]);
    vo.z = f2bf(Vl[c * 65 + k0 + 2]);
    vo.w = f2bf(Vl[c * 65 + k0 + 3]);
    *(ushort4*)(vdst + c * 64 + chunk * 8 + (k0 & 7)) = vo;
  }
}

// ---------------- main: flash attention, QB=128, double-buffered global_load_lds ----------
__global__ __launch_bounds__(256) void sdpa_fwd2(
    const float* __restrict__ Qg, const ushort_t* __restrict__ Kws,
    const ushort_t* __restrict__ Vws, float* __restrict__ Og) {
  __shared__ __align__(16) ushort_t Kl[2][TILE_ELEMS];
  __shared__ __align__(16) ushort_t Vt[2][TILE_ELEMS];
  __shared__ __align__(16) ushort_t Pl[4][32 * 64];   // per-wave 32x64, swizzled

  const int tid  = threadIdx.x;
  const int w    = tid >> 6;
  const int lane = tid & 63;
  const int lg   = lane >> 4;
  const int li   = lane & 15;
  const int head = blockIdx.y;
  const int q0   = blockIdx.x * QB;
  const size_t base = (size_t)head * S_LEN * DH;
  const ushort_t* ksrc = Kws + (size_t)head * HEAD_WS;
  const ushort_t* vsrc = Vws + (size_t)head * HEAD_WS;

  // Q A-frags, pre-scaled by (1/8)*log2(e): rows w*32+m*16+li, k = s*32+lg*8+j
  bf16x8 aq[2][2];
#pragma unroll
  for (int m = 0; m < 2; ++m) {
    const float* qp = Qg + base + (size_t)(q0 + w * 32 + m * 16 + li) * DH;
#pragma unroll
    for (int s = 0; s < 2; ++s) {
      union { ushort_t u[8]; bf16x8 v; } t;
      const float* p = qp + s * 32 + lg * 8;
      float4 f0 = *(const float4*)p;
      float4 f1 = *(const float4*)(p + 4);
      t.u[0] = f2bf(f0.x * QSCALE); t.u[1] = f2bf(f0.y * QSCALE);
      t.u[2] = f2bf(f0.z * QSCALE); t.u[3] = f2bf(f0.w * QSCALE);
      t.u[4] = f2bf(f1.x * QSCALE); t.u[5] = f2bf(f1.y * QSCALE);
      t.u[6] = f2bf(f1.z * QSCALE); t.u[7] = f2bf(f1.w * QSCALE);
      aq[m][s] = t.v;
    }
  }

  f32x4 oacc[2][4];
  float lrow[2][4];
#pragma unroll
  for (int m = 0; m < 2; ++m) {
#pragma unroll
    for (int n = 0; n < 4; ++n) oacc[m][n] = (f32x4){0.f, 0.f, 0.f, 0.f};
#pragma unroll
    for (int r = 0; r < 4; ++r) lrow[m][r] = 0.f;
  }

  ushort_t* Pw = Pl[w];

  // prologue: stage tile 0 into buf 0
  {
    const ushort_t* ks = ksrc + w * 512 + lane * 8;
    const ushort_t* vs = vsrc + w * 512 + lane * 8;
    gl_lds16(ks,        &Kl[0][w * 512]);
    gl_lds16(ks + 2048, &Kl[0][2048 + w * 512]);
    gl_lds16(vs,        &Vt[0][w * 512]);
    gl_lds16(vs + 2048, &Vt[0][2048 + w * 512]);
  }
  __syncthreads();

#pragma unroll 1
  for (int t = 0; t < NT; ++t) {
    const int cur = t & 1;
    if (t + 1 < NT) {  // prefetch next tile into other buffer
      const ushort_t* ks = ksrc + (t + 1) * TILE_ELEMS + w * 512 + lane * 8;
      const ushort_t* vs = vsrc + (t + 1) * TILE_ELEMS + w * 512 + lane * 8;
      gl_lds16(ks,        &Kl[cur ^ 1][w * 512]);
      gl_lds16(ks + 2048, &Kl[cur ^ 1][2048 + w * 512]);
      gl_lds16(vs,        &Vt[cur ^ 1][w * 512]);
      gl_lds16(vs + 2048, &Vt[cur ^ 1][2048 + w * 512]);
    }
    const ushort_t* Kc = Kl[cur];
    const ushort_t* Vc = Vt[cur];

    // ---- S = Q K^T (S already in log2 domain) ----
    f32x4 sa[2][4];
#pragma unroll
    for (int m = 0; m < 2; ++m)
#pragma unroll
      for (int n = 0; n < 4; ++n) sa[m][n] = (f32x4){0.f, 0.f, 0.f, 0.f};
#pragma unroll
    for (int n = 0; n < 4; ++n) {
#pragma unroll
      for (int s = 0; s < 2; ++s) {
        bf16x8 bk = *(const bf16x8*)((const char*)Kc + (n * 16 + li) * 128 +
                                     (((s * 4 + lg) ^ (li & 7)) << 4));
        sa[0][n] = __builtin_amdgcn_mfma_f32_16x16x32_bf16(aq[0][s], bk, sa[0][n], 0, 0, 0);
        sa[1][n] = __builtin_amdgcn_mfma_f32_16x16x32_bf16(aq[1][s], bk, sa[1][n], 0, 0, 0);
      }
    }

    // ---- p = exp2(S); accumulate l; scatter P to per-wave swizzled LDS ----
#pragma unroll
    for (int m = 0; m < 2; ++m) {
#pragma unroll
      for (int n = 0; n < 4; ++n) {
#pragma unroll
        for (int r = 0; r < 4; ++r) {
          float pv = EXP2(sa[m][n][r]);
          lrow[m][r] += pv;
          int row = m * 16 + lg * 4 + r;
          int col = n * 16 + li;
          *(ushort_t*)((char*)Pw + row * 128 + ((((col >> 3) ^ (row & 7))) << 4) +
                       (col & 7) * 2) = bf_hu(pv);
        }
      }
    }

    // ---- reload P as A-frags ----
    bf16x8 ap[2][2];
#pragma unroll
    for (int m = 0; m < 2; ++m)
#pragma unroll
      for (int s = 0; s < 2; ++s)
        ap[m][s] = *(const bf16x8*)((const char*)Pw + (m * 16 + li) * 128 +
                                    (((s * 4 + lg) ^ (li & 7)) << 4));

    // ---- O += P V ----
#pragma unroll
    for (int n = 0; n < 4; ++n) {
#pragma unroll
      for (int s = 0; s < 2; ++s) {
        bf16x8 bv = *(const bf16x8*)((const char*)Vc + (n * 16 + li) * 128 +
                                     (((s * 4 + lg) ^ (li & 7)) << 4));
        oacc[0][n] = __builtin_amdgcn_mfma_f32_16x16x32_bf16(ap[0][s], bv, oacc[0][n], 0, 0, 0);
        oacc[1][n] = __builtin_amdgcn_mfma_f32_16x16x32_bf16(ap[1][s], bv, oacc[1][n], 0, 0, 0);
      }
    }

    __syncthreads();  // drains our global_load_lds (vmcnt) + all waves' LDS reads
  }

  // ---- epilogue: reduce l across the 16 lanes of each row group, write O ----
#pragma unroll
  for (int m = 0; m < 2; ++m) {
#pragma unroll
    for (int r = 0; r < 4; ++r) {
      float l = lrow[m][r];
      l += __shfl_xor(l, 1);
      l += __shfl_xor(l, 2);
      l += __shfl_xor(l, 4);
      l += __shfl_xor(l, 8);
      float inv = 1.0f / l;
      size_t ro = base + (size_t)(q0 + w * 32 + m * 16 + lg * 4 + r) * DH;
#pragma unroll
      for (int n = 0; n < 4; ++n)
        Og[ro + n * 16 + li] = oacc[m][n][r] * inv;
    }
  }
}

// ---------------- round-1 fallback (used only if ws too small) ----------------
#define LSTR 72
__global__ __launch_bounds__(256) void sdpa_fwd_v1(
    const float* __restrict__ Qg, const float* __restrict__ Kg,
    const float* __restrict__ Vg, float* __restrict__ Og) {
  __shared__ __align__(16) ushort_t Klv[KB * LSTR];
  __shared__ __align__(16) ushort_t Vtv[DH * LSTR];
  __shared__ __align__(16) ushort_t Plv[4 * 16 * LSTR];
  const int tid = threadIdx.x;
  const int w = tid >> 6, lane = tid & 63, lg = lane >> 4, li = lane & 15;
  const int bh = blockIdx.y;
  const int q0 = blockIdx.x * 64;
  const size_t base = (size_t)bh * S_LEN * DH;
  bf16x8 aq[2];
  {
    const float* qrow = Qg + base + (size_t)(q0 + w * 16 + li) * DH;
    for (int s = 0; s < 2; ++s) {
      union { ushort_t u[8]; bf16x8 v; } t;
      const float* p = qrow + s * 32 + lg * 8;
      float4 f0 = *(const float4*)(p);
      float4 f1 = *(const float4*)(p + 4);
      t.u[0] = f2bf(f0.x * 0.125f); t.u[1] = f2bf(f0.y * 0.125f);
      t.u[2] = f2bf(f0.z * 0.125f); t.u[3] = f2bf(f0.w * 0.125f);
      t.u[4] = f2bf(f1.x * 0.125f); t.u[5] = f2bf(f1.y * 0.125f);
      t.u[6] = f2bf(f1.z * 0.125f); t.u[7] = f2bf(f1.w * 0.125f);
      aq[s] = t.v;
    }
  }
  f32x4 oacc[4]; float mrow[4], lrow[4];
  for (int n = 0; n < 4; ++n) oacc[n] = (f32x4){0.f, 0.f, 0.f, 0.f};
  for (int r = 0; r < 4; ++r) { mrow[r] = -1e30f; lrow[r] = 0.f; }
  ushort_t* Pw = &Plv[w * 16 * LSTR];
  for (int kv0 = 0; kv0 < S_LEN; kv0 += KB) {
    __syncthreads();
    for (int i = 0; i < 4; ++i) {
      int f4 = tid + i * 256;
      int row = f4 >> 4, c0 = (f4 & 15) * 4;
      size_t goff = base + (size_t)(kv0 + row) * DH + c0;
      float4 kd = *(const float4*)(Kg + goff);
      float4 vd = *(const float4*)(Vg + goff);
      ushort_t* kp = &Klv[row * LSTR + c0];
      kp[0] = f2bf(kd.x); kp[1] = f2bf(kd.y); kp[2] = f2bf(kd.z); kp[3] = f2bf(kd.w);
      Vtv[(c0 + 0) * LSTR + row] = f2bf(vd.x);
      Vtv[(c0 + 1) * LSTR + row] = f2bf(vd.y);
      Vtv[(c0 + 2) * LSTR + row] = f2bf(vd.z);
      Vtv[(c0 + 3) * LSTR + row] = f2bf(vd.w);
    }
    __syncthreads();
    f32x4 sa[4];
    for (int n = 0; n < 4; ++n) sa[n] = (f32x4){0.f, 0.f, 0.f, 0.f};
    for (int n = 0; n < 4; ++n)
      for (int s = 0; s < 2; ++s) {
        bf16x8 bk = *(const bf16x8*)&Klv[(n * 16 + li) * LSTR + s * 32 + lg * 8];
        sa[n] = __builtin_amdgcn_mfma_f32_16x16x32_bf16(aq[s], bk, sa[n], 0, 0, 0);
      }
    float mt[4];
    for (int r = 0; r < 4; ++r)
      mt[r] = fmaxf(fmaxf(sa[0][r], sa[1][r]), fmaxf(sa[2][r], sa[3][r]));
    for (int mask = 1; mask < 16; mask <<= 1)
      for (int r = 0; r < 4; ++r) mt[r] = fmaxf(mt[r], __shfl_xor(mt[r], mask));
    float alpha[4];
    for (int r = 0; r < 4; ++r) {
      float mn = fmaxf(mrow[r], mt[r]);
      alpha[r] = __expf(mrow[r] - mn);
      mrow[r] = mn;
    }
    float p[4][4], ps[4];
    for (int n = 0; n < 4; ++n)
      for (int r = 0; r < 4; ++r) p[n][r] = __expf(sa[n][r] - mrow[r]);
    for (int r = 0; r < 4; ++r) ps[r] = (p[0][r] + p[1][r]) + (p[2][r] + p[3][r]);
    for (int mask = 1; mask < 16; mask <<= 1)
      for (int r = 0; r < 4; ++r) ps[r] += __shfl_xor(ps[r], mask);
    for (int r = 0; r < 4; ++r) lrow[r] = lrow[r] * alpha[r] + ps[r];
    for (int n = 0; n < 4; ++n)
      for (int r = 0; r < 4; ++r) oacc[n][r] *= alpha[r];
    for (int n = 0; n < 4; ++n)
      for (int r = 0; r < 4; ++r)
        Pw[(lg * 4 + r) * LSTR + n * 16 + li] = f2bf(p[n][r]);
    bf16x8 ap[2];
    for (int s = 0; s < 2; ++s)
      ap[s] = *(const bf16x8*)&Pw[li * LSTR + s * 32 + lg * 8];
    for (int n = 0; n < 4; ++n)
      for (int s = 0; s < 2; ++s) {
        bf16x8 bv = *(const bf16x8*)&Vtv[(n * 16 + li) * LSTR + s * 32 + lg * 8];
        oacc[n] = __builtin_amdgcn_mfma_f32_16x16x32_bf16(ap[s], bv, oacc[n], 0, 0, 0);
      }
  }
  for (int r = 0; r < 4; ++r) {
    float inv = 1.0f / lrow[r];
    size_t rowoff = base + (size_t)(q0 + w * 16 + lg * 4 + r) * DH;
    for (int n = 0; n < 4; ++n) Og[rowoff + n * 16 + li] = oacc[n][r] * inv;
  }
}

extern "C" void kernel_launch(void* const* d_in, const int* in_sizes, int n_in,
                              void* d_out, int out_size, void* d_ws, size_t ws_size,
                              hipStream_t stream) {
  const float* Qg = (const float*)d_in[0];
  const float* Kg = (const float*)d_in[1];
  const float* Vg = (const float*)d_in[2];
  float* Og = (float*)d_out;
  if (ws_size >= WS_NEEDED) {
    ushort_t* Kws = (ushort_t*)d_ws;
    ushort_t* Vws = Kws + (size_t)NH * HEAD_WS;
    prep_kv<<<dim3(NT, NH), 256, 0, stream>>>(Kg, Vg, Kws, Vws);
    sdpa_fwd2<<<dim3(S_LEN / QB, NH), 256, 0, stream>>>(Qg, Kws, Vws, Og);
  } else {
    sdpa_fwd_v1<<<dim3(S_LEN / 64, NH), 256, 0, stream>>>(Qg, Kg, Vg, Og);
  }
}